// Round 4
// baseline (813.954 us; speedup 1.0000x reference)
//
#include <hip/hip_runtime.h>
#include <math.h>

#define T_TOK 4096
#define D_DIM 1024

typedef __attribute__((ext_vector_type(4))) float f32x4;
typedef __attribute__((ext_vector_type(8))) short s16x8;

__device__ __forceinline__ unsigned short f2bf(float f){
  union { float f; unsigned u; } v; v.f = f;
  unsigned r = v.u + 0x7FFFu + ((v.u >> 16) & 1u);   // RNE; inputs finite
  return (unsigned short)(r >> 16);
}

// ---------------- router: fp64 logits, argmax, w_t, aux-loss sums ----------------
__global__ __launch_bounds__(256) void router_kernel(
    const float* __restrict__ x, const float* __restrict__ gumbel,
    const float* __restrict__ rw, const float* __restrict__ rb,
    int* __restrict__ expert_id, float* __restrict__ wtok,
    double* __restrict__ prob_sums, int* __restrict__ counts)
{
  __shared__ float sprob[4][8];
  int wave = threadIdx.x >> 6, lane = threadIdx.x & 63;
  int t = blockIdx.x * 4 + wave;
  const float* xr = x + (size_t)t * D_DIM;
  double acc[8];
  #pragma unroll
  for (int e = 0; e < 8; e++) acc[e] = 0.0;
  #pragma unroll
  for (int i = 0; i < 16; i++){
    int d = i * 64 + lane;
    double xv = (double)xr[d];
    const float4* rwp = (const float4*)(rw + (size_t)d * 8);
    float4 r0 = rwp[0], r1 = rwp[1];
    acc[0] += xv * (double)r0.x; acc[1] += xv * (double)r0.y;
    acc[2] += xv * (double)r0.z; acc[3] += xv * (double)r0.w;
    acc[4] += xv * (double)r1.x; acc[5] += xv * (double)r1.y;
    acc[6] += xv * (double)r1.z; acc[7] += xv * (double)r1.w;
  }
  #pragma unroll
  for (int e = 0; e < 8; e++){
    #pragma unroll
    for (int off = 32; off; off >>= 1) acc[e] += __shfl_xor(acc[e], off);
  }
  double logit[8], z[8];
  #pragma unroll
  for (int e = 0; e < 8; e++){
    logit[e] = acc[e] + (double)rb[e];
    z[e] = logit[e] + (double)gumbel[(size_t)t * 8 + e];
  }
  int amax = 0;
  #pragma unroll
  for (int e = 1; e < 8; e++) if (z[e] > z[amax]) amax = e;   // first-max like jnp.argmax
  float zm = (float)z[amax];
  float se = 0.f;
  #pragma unroll
  for (int e = 0; e < 8; e++) se += expf((float)z[e] - zm);
  float y = 1.f / se;                 // y_soft at argmax
  float w = (1.0f - y) + y;           // replicate ref fp32 arithmetic
  double lm = logit[0];
  #pragma unroll
  for (int e = 1; e < 8; e++) lm = fmax(lm, logit[e]);
  float p[8]; float ps = 0.f;
  #pragma unroll
  for (int e = 0; e < 8; e++){ p[e] = expf((float)(logit[e] - lm)); ps += p[e]; }
  float inv = 1.f / ps;

  if (lane == 0){
    expert_id[t] = amax; wtok[t] = w;
    atomicAdd(&counts[amax], 1);
    #pragma unroll
    for (int e = 0; e < 8; e++) sprob[wave][e] = p[e] * inv;
  }
  __syncthreads();
  if (threadIdx.x < 8){
    double s = (double)sprob[0][threadIdx.x] + (double)sprob[1][threadIdx.x]
             + (double)sprob[2][threadIdx.x] + (double)sprob[3][threadIdx.x];
    atomicAdd(&prob_sums[threadIdx.x], s);
  }
}

// ---------------- finalize: offsets/cursors + aux loss ----------------
__global__ void finalize_kernel(const double* __restrict__ prob_sums, const int* __restrict__ counts,
                                int* __restrict__ offsets, int* __restrict__ cursor,
                                float* __restrict__ aux_out)
{
  if (threadIdx.x == 0){
    int off = 0; double aux = 0.0;
    for (int e = 0; e < 8; e++){ offsets[e] = off; cursor[e] = off; off += counts[e]; }
    for (int e = 0; e < 8; e++){
      double imp = prob_sums[e] / 4096.0;
      double d = imp - 0.125;
      aux += d * d;
    }
    aux_out[0] = (float)(aux / 8.0);
  }
}

// ---------------- scatter: counting-sort tokens + x -> bf16 grouped ----------------
__global__ __launch_bounds__(256) void scatter_kernel(
    const float* __restrict__ x, const int* __restrict__ expert_id, const float* __restrict__ wtok,
    int* __restrict__ cursor, int* __restrict__ token_of, float* __restrict__ gw,
    unsigned short* __restrict__ Xg)
{
  int t = blockIdx.x;
  __shared__ int spos;
  if (threadIdx.x == 0){
    int e = expert_id[t];
    int p = atomicAdd(&cursor[e], 1);
    spos = p;
    token_of[p] = t; gw[p] = wtok[t];
  }
  __syncthreads();
  int pos = spos;
  float4 v = ((const float4*)(x + (size_t)t * D_DIM))[threadIdx.x];
  ushort4 o; o.x = f2bf(v.x); o.y = f2bf(v.y); o.z = f2bf(v.z); o.w = f2bf(v.w);
  ((ushort4*)(Xg + (size_t)pos * D_DIM))[threadIdx.x] = o;
}

// ---------------- grouped GEMM with fused fp32->bf16 weight transpose ----------------
// C[m][n] = act( A[m][:] . W[:][n] + bias[n] ), contraction over K.
// A: bf16 [T][K] (k-contiguous, grouped rows). W: fp32 [E][K][N] natural (n-contiguous).
// 128x128 tile, BK=32, 256 threads (2x2 waves of 64x64), mfma 16x16x32 bf16.
// VGPR-staged software pipeline: global->regs (private, no vmcnt drain at barrier),
// regs->LDS (bf16, B transposed to n-major), ONE barrier per K-step, dbuf LDS.
// LDS rows padded to 40 shorts (80 B): fragment ds_read_b128 ~2-way conflicts (free).
template<int K, int KL, int N, int PASS2>
__global__ __launch_bounds__(256) void ffn_gemm(
    const unsigned short* __restrict__ A,
    const float* __restrict__ W,
    const float* __restrict__ bias,
    const int* __restrict__ counts, const int* __restrict__ offsets,
    const int* __restrict__ token_of, const float* __restrict__ gw,
    unsigned short* __restrict__ Hout,   // PASS2=0: bf16 gelu output (grouped rows)
    float* __restrict__ Fout)            // PASS2=1: fp32 atomic-combine, scattered rows
{
  int e = blockIdx.z;
  int cnt = counts[e];
  int by = blockIdx.y;
  if (by * 128 >= cnt) return;            // uniform early-exit
  int offs = offsets[e];
  int bx = PASS2 ? (blockIdx.x & 7) : blockIdx.x;
  int ks = PASS2 ? (blockIdx.x >> 3) : 0;
  int tid = threadIdx.x;
  int lane = tid & 63;
  int wv = __builtin_amdgcn_readfirstlane(tid >> 6);
  int wm = wv & 1, wn = wv >> 1;

  __shared__ unsigned short sA[2][128 * 40];   // 10 KB each
  __shared__ unsigned short sB[2][128 * 40];

  // ---- A staging: thread covers rows r, r+64 (r = tid>>2), 16B seg s = tid&3
  int rA = tid >> 2, sA4 = tid & 3;
  size_t aoff[2];
  #pragma unroll
  for (int h = 0; h < 2; h++){
    int pos = offs + by * 128 + rA + h * 64;
    if (pos > T_TOK - 1) pos = T_TOK - 1;          // clamp; masked at store
    aoff[h] = (size_t)pos * K + (size_t)ks * KL + sA4 * 8;
  }
  // ---- B staging: thread covers n-pair (2g, 2g+1), k-octet kq*8..kq*8+7
  int g = tid >> 2, kq = tid & 3;
  int nloc = 2 * g;
  const float* wp = W + (size_t)e * K * N + ((size_t)ks * KL + kq * 8) * N
                    + (size_t)bx * 128 + nloc;

  uint4 ra[2];
  float2 rb2[8];

  auto loadTile = [&](int kt){
    #pragma unroll
    for (int h = 0; h < 2; h++)
      ra[h] = *(const uint4*)(A + aoff[h] + kt * 32);
    const float* bp = wp + (size_t)kt * 32 * N;
    #pragma unroll
    for (int i = 0; i < 8; i++)
      rb2[i] = *(const float2*)(bp + (size_t)i * N);
  };

  f32x4 accv[4][4];
  #pragma unroll
  for (int mi = 0; mi < 4; mi++)
    #pragma unroll
    for (int ni = 0; ni < 4; ni++) accv[mi][ni] = (f32x4){0.f, 0.f, 0.f, 0.f};

  loadTile(0);

  int col = lane & 15, quad = lane >> 4;
  const int NK = KL / 32;
  for (int kt = 0; kt < NK; ++kt){
    int buf = kt & 1;
    // regs -> LDS (waits vmcnt for tile kt's loads; they had a full MFMA phase in flight)
    #pragma unroll
    for (int h = 0; h < 2; h++)
      *(uint4*)&sA[buf][(rA + h * 64) * 40 + sA4 * 8] = ra[h];
    #pragma unroll
    for (int j = 0; j < 2; j++){
      unsigned pk[4];
      #pragma unroll
      for (int i2 = 0; i2 < 4; i2++){
        float lo = (j == 0) ? rb2[2 * i2].x     : rb2[2 * i2].y;
        float hi = (j == 0) ? rb2[2 * i2 + 1].x : rb2[2 * i2 + 1].y;
        pk[i2] = (unsigned)f2bf(lo) | ((unsigned)f2bf(hi) << 16);
      }
      *(uint4*)&sB[buf][(nloc + j) * 40 + kq * 8] = *(uint4*)pk;
    }
    if (kt + 1 < NK) loadTile(kt + 1);   // refill regs; in flight through MFMA phase
    __syncthreads();                     // lgkmcnt-only drain (no global_load_lds!)
    s16x8 af[4], bf[4];
    #pragma unroll
    for (int mi = 0; mi < 4; mi++)
      af[mi] = *(const s16x8*)&sA[buf][(wm * 64 + mi * 16 + col) * 40 + quad * 8];
    #pragma unroll
    for (int ni = 0; ni < 4; ni++)
      bf[ni] = *(const s16x8*)&sB[buf][(wn * 64 + ni * 16 + col) * 40 + quad * 8];
    #pragma unroll
    for (int mi = 0; mi < 4; mi++)
      #pragma unroll
      for (int ni = 0; ni < 4; ni++)
        accv[mi][ni] = __builtin_amdgcn_mfma_f32_16x16x32_bf16(af[mi], bf[ni], accv[mi][ni], 0, 0, 0);
  }

  float bv[4];
  #pragma unroll
  for (int ni = 0; ni < 4; ni++)
    bv[ni] = bias[(size_t)e * N + bx * 128 + wn * 64 + ni * 16 + col];

  if (PASS2 == 0){
    #pragma unroll
    for (int mi = 0; mi < 4; mi++){
      int rbase = by * 128 + wm * 64 + mi * 16 + quad * 4;
      #pragma unroll
      for (int r = 0; r < 4; r++){
        int row = rbase + r;
        if (row < cnt){
          size_t orow = (size_t)(offs + row) * N + bx * 128 + wn * 64 + col;
          #pragma unroll
          for (int ni = 0; ni < 4; ni++){
            float v = accv[mi][ni][r] + bv[ni];
            float gl = 0.5f * v * (1.0f + erff(v * 0.70710678118654752f));  // exact gelu
            Hout[orow + ni * 16] = f2bf(gl);
          }
        }
      }
    }
  } else {
    #pragma unroll
    for (int mi = 0; mi < 4; mi++){
      int rbase = by * 128 + wm * 64 + mi * 16 + quad * 4;
      #pragma unroll
      for (int r = 0; r < 4; r++){
        int row = rbase + r;
        if (row < cnt){
          int pos = offs + row;
          int tok = token_of[pos];
          float wgt = gw[pos];
          size_t orow = (size_t)tok * N + bx * 128 + wn * 64 + col;
          #pragma unroll
          for (int ni = 0; ni < 4; ni++){
            float v = accv[mi][ni][r];
            if (ks == 0) v += bv[ni];
            atomicAdd(&Fout[orow + ni * 16], v * wgt);
          }
        }
      }
    }
  }
}

extern "C" void kernel_launch(void* const* d_in, const int* in_sizes, int n_in,
                              void* d_out, int out_size, void* d_ws, size_t ws_size,
                              hipStream_t stream)
{
  const float* x      = (const float*)d_in[0];
  const float* gumbel = (const float*)d_in[1];
  const float* rw     = (const float*)d_in[2];
  const float* rb     = (const float*)d_in[3];
  const float* w1     = (const float*)d_in[4];
  const float* b1     = (const float*)d_in[5];
  const float* w2     = (const float*)d_in[6];
  const float* b2     = (const float*)d_in[7];
  float* out = (float*)d_out;

  char* ws = (char*)d_ws;
  double* prob_sums = (double*)(ws + 0);     // 64 B
  int* counts    = (int*)(ws + 64);
  int* offsets   = (int*)(ws + 96);
  int* cursor    = (int*)(ws + 128);
  int* expert_id = (int*)(ws + 256);                    // 16 KB
  float* wtok    = (float*)(ws + 256 + 16384);          // 16 KB
  int* token_of  = (int*)(ws + 256 + 2 * 16384);        // 16 KB
  float* gw      = (float*)(ws + 256 + 3 * 16384);      // 16 KB -> ends at 65792
  unsigned short* Xg     = (unsigned short*)(ws + 65792);             // 8 MiB bf16
  unsigned short* hidden = (unsigned short*)(ws + 65792 + 8388608);   // 32 MiB bf16

  hipMemsetAsync(ws, 0, 256, stream);                               // atomic accumulators
  hipMemsetAsync(out, 0, (size_t)out_size * sizeof(float), stream); // ffn2 atomicAdd target

  router_kernel<<<1024, 256, 0, stream>>>(x, gumbel, rw, rb, expert_id, wtok, prob_sums, counts);
  finalize_kernel<<<1, 64, 0, stream>>>(prob_sums, counts, offsets, cursor, out + 4194304);
  scatter_kernel<<<4096, 256, 0, stream>>>(x, expert_id, wtok, cursor, token_of, gw, Xg);

  // hidden = gelu(Xg @ w1[e] + b1[e])   (M=cnt_e, N=4096, K=1024), fused w1 fp32->bf16 transpose
  ffn_gemm<1024, 1024, 4096, 0><<<dim3(32, 32, 8), 256, 0, stream>>>(
      Xg, w1, b1, counts, offsets, nullptr, nullptr, hidden, nullptr);

  // out[tok] += w_t * (hidden @ w2[e] + b2[e])  (N=1024, K=4096), split-K=2, fused transpose
  ffn_gemm<4096, 2048, 1024, 1><<<dim3(16, 32, 8), 256, 0, stream>>>(
      hidden, w2, b2, counts, offsets, token_of, gw, nullptr, out);
}